// Round 4
// baseline (54.662 us; speedup 1.0000x reference)
//
#include <hip/hip_runtime.h>
#include <hip/hip_bf16.h>

static constexpr int BLOCK     = 256;
static constexpr int GRID_MAIN = 2048;
static constexpr int UNROLL    = 4;

typedef float f32x4 __attribute__((ext_vector_type(4)));

__device__ __forceinline__ float patch_nan(float x) {
    return (x != x) ? 1e-6f : x;
}

// non-target term: -(1-alpha) * p^2 * ln(1-p)   (alpha = 0.25)
__device__ __forceinline__ float neg_term(float x) {
    return -0.75f * x * x * __logf(1.0f - x);
}

// target term: -alpha * (1-p)^2 * ln(p)
__device__ __forceinline__ float pos_term(float x) {
    float om = 1.0f - x;
    return -0.25f * om * om * __logf(x);
}

// Block-wide sum; result valid in thread 0 only.
__device__ __forceinline__ float block_reduce_sum(float v) {
    #pragma unroll
    for (int off = 32; off > 0; off >>= 1)
        v += __shfl_down(v, off, 64);
    __shared__ float smem[BLOCK / 64];
    const int lane = threadIdx.x & 63;
    const int wid  = threadIdx.x >> 6;
    if (lane == 0) smem[wid] = v;
    __syncthreads();
    float r = 0.0f;
    if (threadIdx.x == 0) {
        #pragma unroll
        for (int i = 0; i < BLOCK / 64; ++i) r += smem[i];
    }
    return r;
}

__device__ __forceinline__ float elem_contrib(float x0, float x1, float x2, float x3,
                                              int i, int shiftC4, int maskC4,
                                              const int* __restrict__ classes) {
    float a = neg_term(x0) + neg_term(x1) + neg_term(x2) + neg_term(x3);
    const int row     = i >> shiftC4;
    const int colbase = (i & maskC4) << 2;
    const unsigned d  = (unsigned)(classes[row] - colbase);
    if (d < 4u) {  // target column falls inside this float4
        float x = (d == 0) ? x0 : (d == 1) ? x1 : (d == 2) ? x2 : x3;
        a += pos_term(x) - neg_term(x);
    }
    return a;
}

// Fused pass, 4-deep software pipeline: issue 4 independent float4 loads
// (4 KB/wave in flight) before consuming, so HBM latency is covered by
// outstanding loads instead of serial load->compute->load per wave.
__global__ void __launch_bounds__(BLOCK)
focal_fused(const f32x4* __restrict__ p4, const int* __restrict__ classes,
            float* __restrict__ partials, int n4, int shiftC4) {
    float acc = 0.0f;
    const int maskC4 = (1 << shiftC4) - 1;
    const int S      = gridDim.x * blockDim.x;
    int i0 = blockIdx.x * blockDim.x + threadIdx.x;

    for (; i0 + (UNROLL - 1) * S < n4; i0 += UNROLL * S) {
        f32x4 v[UNROLL];
        #pragma unroll
        for (int u = 0; u < UNROLL; ++u)
            v[u] = __builtin_nontemporal_load(&p4[i0 + u * S]);
        #pragma unroll
        for (int u = 0; u < UNROLL; ++u) {
            acc += elem_contrib(patch_nan(v[u].x), patch_nan(v[u].y),
                                patch_nan(v[u].z), patch_nan(v[u].w),
                                i0 + u * S, shiftC4, maskC4, classes);
        }
    }
    // tail (not taken for B=32768, C=2048, but keeps the kernel general)
    for (; i0 < n4; i0 += S) {
        f32x4 v = __builtin_nontemporal_load(&p4[i0]);
        acc += elem_contrib(patch_nan(v.x), patch_nan(v.y),
                            patch_nan(v.z), patch_nan(v.w),
                            i0, shiftC4, maskC4, classes);
    }

    float r = block_reduce_sum(acc);
    if (threadIdx.x == 0) partials[blockIdx.x] = r;
}

// Deterministic final reduction of the 2048 partials, scale by 1/B.
__global__ void __launch_bounds__(BLOCK)
focal_final(const float* __restrict__ partials, int n,
            float* __restrict__ out, float invB) {
    float acc = 0.0f;
    for (int i = threadIdx.x; i < n; i += blockDim.x) acc += partials[i];
    float r = block_reduce_sum(acc);
    if (threadIdx.x == 0) out[0] = r * invB;
}

extern "C" void kernel_launch(void* const* d_in, const int* in_sizes, int n_in,
                              void* d_out, int out_size, void* d_ws, size_t ws_size,
                              hipStream_t stream) {
    const float* p       = (const float*)d_in[0];
    const int*   classes = (const int*)d_in[1];
    float*       out     = (float*)d_out;
    float*       ws      = (float*)d_ws;

    const long long N = (long long)in_sizes[0];   // B*C
    const int B  = in_sizes[1];
    const int C  = (int)(N / B);                  // 2048 (power of two)
    const int n4 = (int)(N / 4);
    const int c4 = C / 4;

    int shiftC4 = 0;
    while ((1 << shiftC4) < c4) ++shiftC4;        // log2(C/4) = 9

    focal_fused<<<GRID_MAIN, BLOCK, 0, stream>>>((const f32x4*)p, classes,
                                                 ws, n4, shiftC4);
    focal_final<<<1, BLOCK, 0, stream>>>(ws, GRID_MAIN, out, 1.0f / (float)B);
}